// Round 13
// baseline (256.485 us; speedup 1.0000x reference)
//
#include <hip/hip_runtime.h>
#include <hip/hip_bf16.h>
#include <stdint.h>

#define NB 8
#define LL 4096
#define LQ 2048
#define DD 128

typedef __attribute__((ext_vector_type(8))) short short8;   // bf16x8 MFMA frag
typedef __attribute__((ext_vector_type(4))) short short4v;  // bf16x4
typedef __attribute__((ext_vector_type(4))) float f4;
typedef __attribute__((ext_vector_type(2))) unsigned int u2;

typedef const __attribute__((address_space(1))) unsigned int guint_t;
typedef __attribute__((address_space(3))) unsigned int luint_t;

__device__ __forceinline__ short8 pack8(const float* v) {
    __hip_bfloat16 h[8];
    #pragma unroll
    for (int j = 0; j < 8; ++j) h[j] = __float2bfloat16(v[j]);
    return *(short8*)h;
}

// ---------------------------------------------------------------------------
// Kernel A (MFMA): proj_sw = swizzled(-2 * (x@W^T + b)), projT_sw = unscaled
//   d-major transpose (swizzled), q = avgpool2(x)@W^T + b.  (unchanged, ~8us)
// ---------------------------------------------------------------------------
__global__ __launch_bounds__(256) void projA_kernel(
    const float* __restrict__ x, const float* __restrict__ W,
    const float* __restrict__ bias,
    __hip_bfloat16* __restrict__ proj_sw, __hip_bfloat16* __restrict__ projT_sw,
    __hip_bfloat16* __restrict__ qb, float* __restrict__ qf,
    float* __restrict__ psq, float* __restrict__ qsq)
{
    __shared__ __hip_bfloat16 Wlds[128 * 128];      // 32 KB, XOR-swizzled
    __shared__ __hip_bfloat16 Tt[4][128 * 16];      // 4 KB per-wave transpose tile

    const int tid = threadIdx.x;
    const int lane = tid & 63, w = tid >> 6;
    const int lr = lane & 15, lh = lane >> 4;       // frag row / k-chunk

    #pragma unroll
    for (int k = 0; k < 16; ++k) {
        const int f = k * 1024 + tid * 4;           // flat f32 index
        const int e = f >> 7, col = f & 127;
        f4 v = *(const f4*)&W[f];
        __hip_bfloat16 h[4];
        #pragma unroll
        for (int j = 0; j < 4; ++j) h[j] = __float2bfloat16(v[j]);
        const int byte = e * 256 + (((col * 2)) ^ ((e & 7) << 4));
        *(u2*)((char*)Wlds + byte) = *(u2*)h;
    }
    float bv[8];
    #pragma unroll
    for (int nt = 0; nt < 8; ++nt) bv[nt] = bias[nt * 16 + lr];
    __syncthreads();

    const int tile = blockIdx.x;                    // 768 blocks, 1 tile each
    const int row0 = tile * 64 + w * 16;            // wave's 16 rows
    const bool qmode = tile >= (NB * LL / 64);      // >= 512

    short8 a[4];
    if (!qmode) {
        const float* src = x + (size_t)(row0 + lr) * DD;
        #pragma unroll
        for (int ks = 0; ks < 4; ++ks) {
            float t[8];
            *(f4*)&t[0] = *(const f4*)&src[ks * 32 + lh * 8];
            *(f4*)&t[4] = *(const f4*)&src[ks * 32 + lh * 8 + 4];
            a[ks] = pack8(t);
        }
    } else {
        const int gq = row0 - NB * LL + lr;         // global q row
        const int b = gq >> 11, l = gq & 2047;
        const float* s0 = x + ((size_t)b * LL + 2 * l) * DD;
        #pragma unroll
        for (int ks = 0; ks < 4; ++ks) {
            float t[8];
            f4 u0 = *(const f4*)&s0[ks * 32 + lh * 8];
            f4 u1 = *(const f4*)&s0[ks * 32 + lh * 8 + 4];
            f4 v0 = *(const f4*)&s0[DD + ks * 32 + lh * 8];
            f4 v1 = *(const f4*)&s0[DD + ks * 32 + lh * 8 + 4];
            *(f4*)&t[0] = (u0 + v0) * 0.5f;
            *(f4*)&t[4] = (u1 + v1) * 0.5f;
            a[ks] = pack8(t);
        }
    }

    f4 acc[8] = {};
    #pragma unroll
    for (int nt = 0; nt < 8; ++nt) {
        const int e = nt * 16 + lr;
        #pragma unroll
        for (int ks = 0; ks < 4; ++ks) {
            const int byte = e * 256 + ((ks * 64 + lh * 16) ^ ((lr & 7) << 4));
            short8 bk = *(const short8*)((char*)Wlds + byte);
            acc[nt] = __builtin_amdgcn_mfma_f32_16x16x32_bf16(a[ks], bk, acc[nt], 0, 0, 0);
        }
    }

    __hip_bfloat16 h[8][4];
    f4 rn = {0.f, 0.f, 0.f, 0.f};
    #pragma unroll
    for (int nt = 0; nt < 8; ++nt)
        #pragma unroll
        for (int r = 0; r < 4; ++r) {
            float v = acc[nt][r] + bv[nt];
            acc[nt][r] = v;
            h[nt][r] = __float2bfloat16(v);
            float vb = __bfloat162float(h[nt][r]);
            rn[r] += vb * vb;
        }
    #pragma unroll
    for (int m = 1; m < 16; m <<= 1) {
        #pragma unroll
        for (int r = 0; r < 4; ++r) rn[r] += __shfl_xor(rn[r], m);
    }

    if (!qmode) {
        const int gr = row0;
        // swizzled proj write, PRE-SCALED by -2 (exact): byte = (2d)^((row&7)<<4)
        #pragma unroll
        for (int nt = 0; nt < 8; ++nt)
            #pragma unroll
            for (int r = 0; r < 4; ++r) {
                const int row = gr + lh * 4 + r;
                const int byte = (nt * 32 + lr * 2) ^ (((lh * 4 + r) & 7) << 4);
                *(__hip_bfloat16*)((char*)proj_sw + (size_t)row * 256 + byte) =
                    __float2bfloat16(-2.0f * __bfloat162float(h[nt][r]));
            }
        if (lr == 0) *(f4*)&psq[gr + lh * 4] = rn;
        #pragma unroll
        for (int nt = 0; nt < 8; ++nt) {
            __hip_bfloat16 p[4] = {h[nt][0], h[nt][1], h[nt][2], h[nt][3]};
            *(u2*)((char*)&Tt[w][0] + (nt * 16 + lr) * 32 + lh * 8) = *(u2*)p;
        }
        // projT_sw: row d (8192 B), 128B tile-rows, 8B-block XOR by (d&15)<<3
        const int b = gr >> 12, l0 = gr & 4095;
        #pragma unroll
        for (int i = 0; i < 2; ++i) {
            const int e = lane + i * 64;
            const int sw = (e & 15) << 3;
            char* rowbase = (char*)projT_sw + ((size_t)(b * DD + e)) * (LL * 2)
                          + (size_t)(l0 & ~63) * 2;
            const int ob = (l0 & 63) * 2;           // 16 elems -> 4 x 8B chunks
            #pragma unroll
            for (int c = 0; c < 4; ++c) {
                u2 chunk = *(u2*)((char*)&Tt[w][e * 16] + c * 8);
                *(u2*)(rowbase + ((ob + c * 8) ^ sw)) = chunk;
            }
        }
    } else {
        const int gq = row0 - NB * LL;
        #pragma unroll
        for (int nt = 0; nt < 8; ++nt)
            #pragma unroll
            for (int r = 0; r < 4; ++r) {
                const size_t idx = (size_t)(gq + lh * 4 + r) * DD + nt * 16 + lr;
                qb[idx] = h[nt][r];
                qf[idx] = acc[nt][r];
            }
        if (lr == 0) *(f4*)&qsq[gq + lh * 4] = rn;
    }
}

// ---------------------------------------------------------------------------
// Kernel B: LDS-BW-bound fix. 1024 threads = 8 COMPUTE waves (32 q-rows each,
//   2 mtiles, R9-verified math; staged bytes amortized over 2x MFMAs) +
//   8 HELPER waves (all DMA staging, R8's proven 8-wave stage code, counted
//   vmcnt(4)). Block covers 256 q-rows -> grid/decode/ws IDENTICAL to R11.
//   Register relief vs R9's spill: mt1 q-frags from per-wave swizzled LDS
//   qtile (peak ~116 VGPR < 128 cap at launch_bounds(1024,4)).
// ---------------------------------------------------------------------------
__global__ __launch_bounds__(1024, 4) void fused_kernel(
    const __hip_bfloat16* __restrict__ proj_sw, const __hip_bfloat16* __restrict__ projT_sw,
    const __hip_bfloat16* __restrict__ qb, const float* __restrict__ psq,
    const float* __restrict__ qsq,
    float* __restrict__ pp0, float* __restrict__ pp1,
    float* __restrict__ pp2, float* __restrict__ pp3, int keys_per)
{
    __shared__ __hip_bfloat16 pbuf[2][8192];        // 2 x 16 KB proj tile (swizzled rows)
    __shared__ __hip_bfloat16 tbuf[2][8192];        // 2 x 16 KB projT tile (128B rows, swz)
    __shared__ __hip_bfloat16 qtile[8][2048];       // 8 x 4 KB: compute wave's mt1 q rows
    __shared__ __align__(16) float psbuf[2048];     // 8 KB (covers nsplit=2 too)

    const int bid = blockIdx.x;
    const int b = bid & 7;                          // XCD-pinned batch
    const int qt8 = (bid >> 3) & 7;
    const int ks = bid >> 6;                        // key slice (0..nsplit-1)
    const int tid = threadIdx.x;
    const int w = tid >> 6, lane = tid & 63;        // wave 0..15
    const int lr = lane & 15, lh = lane >> 4;
    const int hw = (w - 8) & 7;                     // helper index (valid for w>=8)

    const int qrow0 = qt8 * 256 + w * 32;           // compute wave's 32 q rows (w<8)
    const int key0 = ks * keys_per;
    const int ntiles = keys_per / 64;               // 64-key phases

    const char* psw = (const char*)proj_sw + (size_t)b * LL * 256;
    const char* ptbsw = (const char*)projT_sw + (size_t)b * DD * LL * 2;
    const float* psb = psq + b * LL;

    // psq slice -> LDS (all threads)
    for (int i = tid; i < keys_per; i += 1024) psbuf[i] = psb[key0 + i];

    // ---- compute-wave prologue: aq0 regs, qn, mt1 q rows -> swizzled qtile ----
    short8 aq0[4];
    float qn0 = 0.f, qn1 = 0.f;
    if (w < 8) {
        const __hip_bfloat16* qbase = qb + ((size_t)b * LQ + qrow0) * DD;
        #pragma unroll
        for (int kss = 0; kss < 4; ++kss)
            aq0[kss] = *(const short8*)&qbase[(size_t)lr * DD + kss * 32 + lh * 8];
        qn0 = qsq[b * LQ + qrow0 + lr];
        qn1 = qsq[b * LQ + qrow0 + 16 + lr];
        // stage mt1 rows (qrow0+16..+31): lane -> row lane&15, 4 x 16B chunks
        const __hip_bfloat16* qsrc = qbase + (size_t)16 * DD;
        const int r = lane & 15;
        #pragma unroll
        for (int i = 0; i < 4; ++i) {
            const int ck = (lane >> 4) * 4 + i;     // 16B chunk 0..15
            short8 v = *(const short8*)&qsrc[(size_t)r * DD + ck * 8];
            const int byte = r * 256 + ((ck * 16) ^ ((r & 7) << 4));
            *(short8*)((char*)&qtile[w][0] + byte) = v;
        }
    }
    __syncthreads();                                // psbuf+qtile visible; vmem drained

    // ---- helper staging (R8's proven 8-wave mapping, w -> hw) ----
    const char* sp = psw + (size_t)key0 * 256 + hw * 2048;
    const char* st = ptbsw + (size_t)(hw * 16 + (lane >> 3)) * (LL * 2)
                   + (size_t)key0 * 2 + (lane & 7) * 16;
    auto stage = [&](int buf) {
        #pragma unroll
        for (int j = 0; j < 2; ++j)
            __builtin_amdgcn_global_load_lds(
                (guint_t*)(sp + j * 1024 + lane * 16),
                (luint_t*)&pbuf[buf][hw * 1024 + j * 512 + lane * 8], 16, 0, 0);
        #pragma unroll
        for (int j = 0; j < 2; ++j)
            __builtin_amdgcn_global_load_lds(
                (guint_t*)(st + (size_t)j * 8 * (LL * 2)),
                (luint_t*)&tbuf[buf][(hw * 16 + j * 8) * 64 + lane * 8], 16, 0, 0);
        sp += 64 * 256;
        st += 64 * 2;
    };
    if (w >= 8) { stage(0); stage(1); }             // 8 outstanding DMAs (helpers)

    f4 oc[2][8] = {};                               // [mt][dt]
    int p = 0;

    for (int t = 0; t < ntiles; ++t) {
        // counted wait (helpers have the DMAs; no-op for compute waves)
        if (t + 1 < ntiles) asm volatile("s_waitcnt vmcnt(4)" ::: "memory");
        else                asm volatile("s_waitcnt vmcnt(0)" ::: "memory");
        asm volatile("s_barrier" ::: "memory");     // B1: phase t data visible

        if (w < 8) {
            #pragma unroll
            for (int sub = 0; sub < 2; ++sub) {
                // ---- GEMM1 (swapped, -2-prescaled K, C-init = qn+pn) ----
                f4 pn0 = *(const f4*)&psbuf[t * 64 + sub * 32 + lh * 4];
                f4 pn1 = *(const f4*)&psbuf[t * 64 + sub * 32 + 16 + lh * 4];
                f4 s00, s01, s10, s11;              // s[kt][mt]
                #pragma unroll
                for (int r = 0; r < 4; ++r) {
                    s00[r] = qn0 + pn0[r];  s01[r] = qn1 + pn0[r];
                    s10[r] = qn0 + pn1[r];  s11[r] = qn1 + pn1[r];
                }
                __builtin_amdgcn_s_setprio(1);
                #pragma unroll
                for (int kss = 0; kss < 4; ++kss) {
                    const int off = (kss * 64 + lh * 16) ^ ((lr & 7) << 4);
                    short8 ak0 = *(const short8*)((const char*)pbuf[p] + (sub * 32 + lr) * 256 + off);
                    short8 ak1 = *(const short8*)((const char*)pbuf[p] + (sub * 32 + 16 + lr) * 256 + off);
                    short8 aq1 = *(const short8*)((const char*)&qtile[w][0] + lr * 256 + off);
                    s00 = __builtin_amdgcn_mfma_f32_16x16x32_bf16(ak0, aq0[kss], s00, 0, 0, 0);
                    s01 = __builtin_amdgcn_mfma_f32_16x16x32_bf16(ak0, aq1, s01, 0, 0, 0);
                    s10 = __builtin_amdgcn_mfma_f32_16x16x32_bf16(ak1, aq0[kss], s10, 0, 0, 0);
                    s11 = __builtin_amdgcn_mfma_f32_16x16x32_bf16(ak1, aq1, s11, 0, 0, 0);
                }
                __builtin_amdgcn_s_setprio(0);

                // ---- transform: power -> exp(-sqrt(max(power,0))) ----
                short8 pa0, pa1;
                {
                    alignas(16) __hip_bfloat16 hh[8];
                    #pragma unroll
                    for (int r = 0; r < 4; ++r) {
                        hh[r]     = __float2bfloat16(__expf(-__builtin_amdgcn_sqrtf(fmaxf(s00[r], 0.0f))));
                        hh[4 + r] = __float2bfloat16(__expf(-__builtin_amdgcn_sqrtf(fmaxf(s10[r], 0.0f))));
                    }
                    pa0 = *(short8*)hh;
                    #pragma unroll
                    for (int r = 0; r < 4; ++r) {
                        hh[r]     = __float2bfloat16(__expf(-__builtin_amdgcn_sqrtf(fmaxf(s01[r], 0.0f))));
                        hh[4 + r] = __float2bfloat16(__expf(-__builtin_amdgcn_sqrtf(fmaxf(s11[r], 0.0f))));
                    }
                    pa1 = *(short8*)hh;
                }

                // ---- GEMM2: B-frag shared across both mtiles ----
                __builtin_amdgcn_s_setprio(1);
                #pragma unroll
                for (int dt = 0; dt < 8; ++dt) {
                    const char* rowp = (const char*)tbuf[p] + (dt * 16 + lr) * 128;
                    const int sw = lr << 3;
                    union { short8 v; short4v h[2]; } u;
                    u.h[0] = *(const short4v*)(rowp + ((lh * 8 + sub * 64) ^ sw));
                    u.h[1] = *(const short4v*)(rowp + ((lh * 8 + 32 + sub * 64) ^ sw));
                    oc[0][dt] = __builtin_amdgcn_mfma_f32_16x16x32_bf16(pa0, u.v, oc[0][dt], 0, 0, 0);
                    oc[1][dt] = __builtin_amdgcn_mfma_f32_16x16x32_bf16(pa1, u.v, oc[1][dt], 0, 0, 0);
                }
                __builtin_amdgcn_s_setprio(0);
            }
        }

        asm volatile("s_barrier" ::: "memory");     // B2: reads of buf[p] done
        if (w >= 8 && t + 2 < ntiles) stage(p);     // refill buf[p] for phase t+2
        p ^= 1;
    }

    // ---- partial O store (compute waves): O[qrow0 + mt*16 + lh*4 + r][dt*16+lr]
    if (w < 8) {
        float* pb = (ks == 0) ? pp0 : (ks == 1) ? pp1 : (ks == 2) ? pp2 : pp3;
        #pragma unroll
        for (int mt = 0; mt < 2; ++mt)
            #pragma unroll
            for (int dt = 0; dt < 8; ++dt)
                #pragma unroll
                for (int r = 0; r < 4; ++r)
                    pb[((size_t)b * LQ + qrow0 + mt * 16 + lh * 4 + r) * DD + dt * 16 + lr]
                        = oc[mt][dt][r];
    }
}

// ---------------------------------------------------------------------------
// Reduce: outk = outv = sum of nsplit partials (p0/p1 alias outk/outv).
// ---------------------------------------------------------------------------
__global__ __launch_bounds__(256) void reduce_kernel(
    const float* __restrict__ p0, const float* __restrict__ p1,
    const float* __restrict__ p2, const float* __restrict__ p3,
    float* __restrict__ outk, float* __restrict__ outv, int nsplit)
{
    const int b = blockIdx.x & 7;
    const size_t j = (size_t)b * (LQ * DD) + ((size_t)(blockIdx.x >> 3) * 256 + threadIdx.x) * 4;
    f4 v = *(const f4*)&p0[j] + *(const f4*)&p1[j];
    if (nsplit == 4) v += *(const f4*)&p2[j] + *(const f4*)&p3[j];
    *(f4*)&outk[j] = v;
    *(f4*)&outv[j] = v;
}

extern "C" void kernel_launch(void* const* d_in, const int* in_sizes, int n_in,
                              void* d_out, int out_size, void* d_ws, size_t ws_size,
                              hipStream_t stream) {
    const float* x = (const float*)d_in[0];
    const float* W = (const float*)d_in[1];
    const float* bias = (const float*)d_in[2];

    float* out = (float*)d_out;
    const size_t NQ = (size_t)NB * LQ * DD;
    float* qf = out;            // output 0: q
    float* outk = out + NQ;     // output 1: k
    float* outv = out + 2 * NQ; // output 2: v

    char* ws = (char*)d_ws;
    __hip_bfloat16* proj  = (__hip_bfloat16*)ws;                          // 8 MB (swizzled, -2x)
    __hip_bfloat16* projT = (__hip_bfloat16*)(ws + 8u * 1024 * 1024);     // 8 MB (swizzled)
    __hip_bfloat16* qb    = (__hip_bfloat16*)(ws + 16u * 1024 * 1024);    // 4 MB
    float* psq            = (float*)(ws + 20u * 1024 * 1024);             // 128 KB
    float* qsq            = (float*)(ws + 20u * 1024 * 1024 + 256u * 1024); // 64 KB
    float* pw2            = (float*)(ws + 24u * 1024 * 1024);             // 8 MB partial
    float* pw3            = (float*)(ws + 32u * 1024 * 1024);             // 8 MB partial

    const int nsplit = (ws_size >= (40ull << 20)) ? 4 : 2;
    const int keys_per = LL / nsplit;

    hipLaunchKernelGGL(projA_kernel, dim3((NB * LL + NB * LQ) / 64), dim3(256), 0, stream,
                       x, W, bias, proj, projT, qb, qf, psq, qsq);
    // grid = 8 batches x 8 q-tiles x nsplit key-slices (matches kernel decode)
    hipLaunchKernelGGL(fused_kernel, dim3(64 * nsplit), dim3(1024), 0, stream,
                       proj, projT, qb, psq, qsq, outk, outv, pw2, pw3, keys_per);
    hipLaunchKernelGGL(reduce_kernel, dim3(2048), dim3(256), 0, stream,
                       outk, outv, pw2, pw3, outk, outv, nsplit);
}

// Round 14
// 77.030 us; speedup vs baseline: 3.3297x; 3.3297x over previous
//
#include <hip/hip_runtime.h>
#include <hip/hip_bf16.h>
#include <stdint.h>

#define NB 8
#define LL 4096
#define LQ 2048
#define DD 128

typedef __attribute__((ext_vector_type(8))) short short8;   // bf16x8 MFMA frag
typedef __attribute__((ext_vector_type(4))) short short4v;  // bf16x4
typedef __attribute__((ext_vector_type(4))) float f4;
typedef __attribute__((ext_vector_type(2))) unsigned int u2;

typedef const __attribute__((address_space(1))) unsigned int guint_t;
typedef __attribute__((address_space(3))) unsigned int luint_t;

__device__ __forceinline__ short8 pack8(const float* v) {
    __hip_bfloat16 h[8];
    #pragma unroll
    for (int j = 0; j < 8; ++j) h[j] = __float2bfloat16(v[j]);
    return *(short8*)h;
}

// ---------------------------------------------------------------------------
// Kernel A (MFMA): proj_sw = swizzled(-2 * (x@W^T + b)), projT_sw = unscaled
//   d-major transpose (swizzled), q = avgpool2(x)@W^T + b.  (unchanged, ~8us)
// ---------------------------------------------------------------------------
__global__ __launch_bounds__(256) void projA_kernel(
    const float* __restrict__ x, const float* __restrict__ W,
    const float* __restrict__ bias,
    __hip_bfloat16* __restrict__ proj_sw, __hip_bfloat16* __restrict__ projT_sw,
    __hip_bfloat16* __restrict__ qb, float* __restrict__ qf,
    float* __restrict__ psq, float* __restrict__ qsq)
{
    __shared__ __hip_bfloat16 Wlds[128 * 128];      // 32 KB, XOR-swizzled
    __shared__ __hip_bfloat16 Tt[4][128 * 16];      // 4 KB per-wave transpose tile

    const int tid = threadIdx.x;
    const int lane = tid & 63, w = tid >> 6;
    const int lr = lane & 15, lh = lane >> 4;       // frag row / k-chunk

    #pragma unroll
    for (int k = 0; k < 16; ++k) {
        const int f = k * 1024 + tid * 4;           // flat f32 index
        const int e = f >> 7, col = f & 127;
        f4 v = *(const f4*)&W[f];
        __hip_bfloat16 h[4];
        #pragma unroll
        for (int j = 0; j < 4; ++j) h[j] = __float2bfloat16(v[j]);
        const int byte = e * 256 + (((col * 2)) ^ ((e & 7) << 4));
        *(u2*)((char*)Wlds + byte) = *(u2*)h;
    }
    float bv[8];
    #pragma unroll
    for (int nt = 0; nt < 8; ++nt) bv[nt] = bias[nt * 16 + lr];
    __syncthreads();

    const int tile = blockIdx.x;                    // 768 blocks, 1 tile each
    const int row0 = tile * 64 + w * 16;            // wave's 16 rows
    const bool qmode = tile >= (NB * LL / 64);      // >= 512

    short8 a[4];
    if (!qmode) {
        const float* src = x + (size_t)(row0 + lr) * DD;
        #pragma unroll
        for (int ks = 0; ks < 4; ++ks) {
            float t[8];
            *(f4*)&t[0] = *(const f4*)&src[ks * 32 + lh * 8];
            *(f4*)&t[4] = *(const f4*)&src[ks * 32 + lh * 8 + 4];
            a[ks] = pack8(t);
        }
    } else {
        const int gq = row0 - NB * LL + lr;         // global q row
        const int b = gq >> 11, l = gq & 2047;
        const float* s0 = x + ((size_t)b * LL + 2 * l) * DD;
        #pragma unroll
        for (int ks = 0; ks < 4; ++ks) {
            float t[8];
            f4 u0 = *(const f4*)&s0[ks * 32 + lh * 8];
            f4 u1 = *(const f4*)&s0[ks * 32 + lh * 8 + 4];
            f4 v0 = *(const f4*)&s0[DD + ks * 32 + lh * 8];
            f4 v1 = *(const f4*)&s0[DD + ks * 32 + lh * 8 + 4];
            *(f4*)&t[0] = (u0 + v0) * 0.5f;
            *(f4*)&t[4] = (u1 + v1) * 0.5f;
            a[ks] = pack8(t);
        }
    }

    f4 acc[8] = {};
    #pragma unroll
    for (int nt = 0; nt < 8; ++nt) {
        const int e = nt * 16 + lr;
        #pragma unroll
        for (int ks = 0; ks < 4; ++ks) {
            const int byte = e * 256 + ((ks * 64 + lh * 16) ^ ((lr & 7) << 4));
            short8 bk = *(const short8*)((char*)Wlds + byte);
            acc[nt] = __builtin_amdgcn_mfma_f32_16x16x32_bf16(a[ks], bk, acc[nt], 0, 0, 0);
        }
    }

    __hip_bfloat16 h[8][4];
    f4 rn = {0.f, 0.f, 0.f, 0.f};
    #pragma unroll
    for (int nt = 0; nt < 8; ++nt)
        #pragma unroll
        for (int r = 0; r < 4; ++r) {
            float v = acc[nt][r] + bv[nt];
            acc[nt][r] = v;
            h[nt][r] = __float2bfloat16(v);
            float vb = __bfloat162float(h[nt][r]);
            rn[r] += vb * vb;
        }
    #pragma unroll
    for (int m = 1; m < 16; m <<= 1) {
        #pragma unroll
        for (int r = 0; r < 4; ++r) rn[r] += __shfl_xor(rn[r], m);
    }

    if (!qmode) {
        const int gr = row0;
        // swizzled proj write, PRE-SCALED by -2 (exact): byte = (2d)^((row&7)<<4)
        #pragma unroll
        for (int nt = 0; nt < 8; ++nt)
            #pragma unroll
            for (int r = 0; r < 4; ++r) {
                const int row = gr + lh * 4 + r;
                const int byte = (nt * 32 + lr * 2) ^ (((lh * 4 + r) & 7) << 4);
                *(__hip_bfloat16*)((char*)proj_sw + (size_t)row * 256 + byte) =
                    __float2bfloat16(-2.0f * __bfloat162float(h[nt][r]));
            }
        if (lr == 0) *(f4*)&psq[gr + lh * 4] = rn;
        #pragma unroll
        for (int nt = 0; nt < 8; ++nt) {
            __hip_bfloat16 p[4] = {h[nt][0], h[nt][1], h[nt][2], h[nt][3]};
            *(u2*)((char*)&Tt[w][0] + (nt * 16 + lr) * 32 + lh * 8) = *(u2*)p;
        }
        // projT_sw: row d (8192 B), 128B tile-rows, 8B-block XOR by (d&15)<<3
        const int b = gr >> 12, l0 = gr & 4095;
        #pragma unroll
        for (int i = 0; i < 2; ++i) {
            const int e = lane + i * 64;
            const int sw = (e & 15) << 3;
            char* rowbase = (char*)projT_sw + ((size_t)(b * DD + e)) * (LL * 2)
                          + (size_t)(l0 & ~63) * 2;
            const int ob = (l0 & 63) * 2;           // 16 elems -> 4 x 8B chunks
            #pragma unroll
            for (int c = 0; c < 4; ++c) {
                u2 chunk = *(u2*)((char*)&Tt[w][e * 16] + c * 8);
                *(u2*)(rowbase + ((ob + c * 8) ^ sw)) = chunk;
            }
        }
    } else {
        const int gq = row0 - NB * LL;
        #pragma unroll
        for (int nt = 0; nt < 8; ++nt)
            #pragma unroll
            for (int r = 0; r < 4; ++r) {
                const size_t idx = (size_t)(gq + lh * 4 + r) * DD + nt * 16 + lr;
                qb[idx] = h[nt][r];
                qf[idx] = acc[nt][r];
            }
        if (lr == 0) *(f4*)&qsq[gq + lh * 4] = rn;
    }
}

// ---------------------------------------------------------------------------
// Kernel B: R9's correctness-verified 2-mtile kernel, given the register
//   budget it needs: __launch_bounds__(512, 2) -> 256-VGPR cap (R9/R12 both
//   spilled at the 128 cap). 8 waves x 32 q-rows = 256 q-rows/block; every
//   staged byte feeds 2x the MFMAs of the 16-wave R11 version -> per-CU LDS
//   reads halve (the measured binding constraint). Grid 256 = 1 block/CU.
// ---------------------------------------------------------------------------
__global__ __launch_bounds__(512, 2) void fused_kernel(
    const __hip_bfloat16* __restrict__ proj_sw, const __hip_bfloat16* __restrict__ projT_sw,
    const __hip_bfloat16* __restrict__ qb, const float* __restrict__ psq,
    const float* __restrict__ qsq,
    float* __restrict__ pp0, float* __restrict__ pp1,
    float* __restrict__ pp2, float* __restrict__ pp3, int keys_per)
{
    __shared__ __hip_bfloat16 pbuf[2][8192];        // 2 x 16 KB proj tile (swizzled rows)
    __shared__ __hip_bfloat16 tbuf[2][8192];        // 2 x 16 KB projT tile (128B rows, swz)
    __shared__ __align__(16) float psbuf[2048];     // 8 KB (covers nsplit=2)

    const int bid = blockIdx.x;
    const int b = bid & 7;                          // XCD-pinned batch
    const int qt8 = (bid >> 3) & 7;
    const int ks = bid >> 6;                        // key slice (0..nsplit-1)
    const int tid = threadIdx.x;
    const int w = tid >> 6, lane = tid & 63;        // wave 0..7
    const int lr = lane & 15, lh = lane >> 4;

    const int qrow0 = qt8 * 256 + w * 32;           // wave's 32 q rows (2 mtiles)
    const int key0 = ks * keys_per;
    const int ntiles = keys_per / 64;               // 64-key phases

    const char* psw = (const char*)proj_sw + (size_t)b * LL * 256;
    const char* ptbsw = (const char*)projT_sw + (size_t)b * DD * LL * 2;
    const float* psb = psq + b * LL;

    // psq slice -> LDS (prologue only; NO global reg-loads inside the loop)
    for (int i = tid; i < keys_per; i += 512) psbuf[i] = psb[key0 + i];

    // q fragments (GEMM1 B-operand), 2 mtiles + norms
    short8 aq[2][4];
    const __hip_bfloat16* qbase = qb + ((size_t)b * LQ + qrow0) * DD;
    #pragma unroll
    for (int mt = 0; mt < 2; ++mt)
        #pragma unroll
        for (int kss = 0; kss < 4; ++kss)
            aq[mt][kss] = *(const short8*)&qbase[(size_t)(mt * 16 + lr) * DD + kss * 32 + lh * 8];
    const float qn0 = qsq[b * LQ + qrow0 + lr];
    const float qn1 = qsq[b * LQ + qrow0 + 16 + lr];

    __syncthreads();                                // psbuf visible; drains prologue vmem

    // staging sources as running pointers (advanced once per stage call)
    const char* sp = psw + (size_t)key0 * 256 + w * 2048;                        // +j*1024
    const char* st = ptbsw + (size_t)(w * 16 + (lane >> 3)) * (LL * 2)
                   + (size_t)key0 * 2 + (lane & 7) * 16;                         // +j*8 rows
    auto stage = [&](int buf) {
        #pragma unroll
        for (int j = 0; j < 2; ++j)
            __builtin_amdgcn_global_load_lds(
                (guint_t*)(sp + j * 1024 + lane * 16),
                (luint_t*)&pbuf[buf][w * 1024 + j * 512 + lane * 8], 16, 0, 0);
        #pragma unroll
        for (int j = 0; j < 2; ++j)
            __builtin_amdgcn_global_load_lds(
                (guint_t*)(st + (size_t)j * 8 * (LL * 2)),
                (luint_t*)&tbuf[buf][(w * 16 + j * 8) * 64 + lane * 8], 16, 0, 0);
        sp += 64 * 256;                             // next 64-key phase
        st += 64 * 2;
    };

    stage(0);
    stage(1);                                       // depth-1 prefetch: 8 outstanding

    f4 oc[2][8] = {};                               // [mt][dt]
    int p = 0;

    for (int t = 0; t < ntiles; ++t) {
        // counted wait: phase t's 4 DMAs done; phase t+1's 4 stay in flight
        if (t + 1 < ntiles) asm volatile("s_waitcnt vmcnt(4)" ::: "memory");
        else                asm volatile("s_waitcnt vmcnt(0)" ::: "memory");
        asm volatile("s_barrier" ::: "memory");     // B1: all waves' t-data visible

        #pragma unroll
        for (int sub = 0; sub < 2; ++sub) {
            // ---- GEMM1 (swapped, -2-prescaled K, C-init = qn+pn -> power) ----
            f4 pn0 = *(const f4*)&psbuf[t * 64 + sub * 32 + lh * 4];
            f4 pn1 = *(const f4*)&psbuf[t * 64 + sub * 32 + 16 + lh * 4];
            f4 s00, s01, s10, s11;                  // s[kt][mt]
            #pragma unroll
            for (int r = 0; r < 4; ++r) {
                s00[r] = qn0 + pn0[r];  s01[r] = qn1 + pn0[r];
                s10[r] = qn0 + pn1[r];  s11[r] = qn1 + pn1[r];
            }
            __builtin_amdgcn_s_setprio(1);
            #pragma unroll
            for (int kss = 0; kss < 4; ++kss) {
                const int off = (kss * 64 + lh * 16) ^ ((lr & 7) << 4);
                short8 ak0 = *(const short8*)((const char*)pbuf[p] + (sub * 32 + lr) * 256 + off);
                short8 ak1 = *(const short8*)((const char*)pbuf[p] + (sub * 32 + 16 + lr) * 256 + off);
                s00 = __builtin_amdgcn_mfma_f32_16x16x32_bf16(ak0, aq[0][kss], s00, 0, 0, 0);
                s01 = __builtin_amdgcn_mfma_f32_16x16x32_bf16(ak0, aq[1][kss], s01, 0, 0, 0);
                s10 = __builtin_amdgcn_mfma_f32_16x16x32_bf16(ak1, aq[0][kss], s10, 0, 0, 0);
                s11 = __builtin_amdgcn_mfma_f32_16x16x32_bf16(ak1, aq[1][kss], s11, 0, 0, 0);
            }
            __builtin_amdgcn_s_setprio(0);

            // ---- transform: power -> exp(-sqrt(max(power,0))), in (0,1] ----
            short8 pa0, pa1;
            {
                alignas(16) __hip_bfloat16 hh[8];
                #pragma unroll
                for (int r = 0; r < 4; ++r) {
                    hh[r]     = __float2bfloat16(__expf(-__builtin_amdgcn_sqrtf(fmaxf(s00[r], 0.0f))));
                    hh[4 + r] = __float2bfloat16(__expf(-__builtin_amdgcn_sqrtf(fmaxf(s10[r], 0.0f))));
                }
                pa0 = *(short8*)hh;
                #pragma unroll
                for (int r = 0; r < 4; ++r) {
                    hh[r]     = __float2bfloat16(__expf(-__builtin_amdgcn_sqrtf(fmaxf(s01[r], 0.0f))));
                    hh[4 + r] = __float2bfloat16(__expf(-__builtin_amdgcn_sqrtf(fmaxf(s11[r], 0.0f))));
                }
                pa1 = *(short8*)hh;
            }

            // ---- GEMM2: O += sim @ proj; B-frag shared across both mtiles ----
            __builtin_amdgcn_s_setprio(1);
            #pragma unroll
            for (int dt = 0; dt < 8; ++dt) {
                const char* rowp = (const char*)tbuf[p] + (dt * 16 + lr) * 128;
                const int sw = lr << 3;
                union { short8 v; short4v h[2]; } u;
                u.h[0] = *(const short4v*)(rowp + ((lh * 8 + sub * 64) ^ sw));
                u.h[1] = *(const short4v*)(rowp + ((lh * 8 + 32 + sub * 64) ^ sw));
                oc[0][dt] = __builtin_amdgcn_mfma_f32_16x16x32_bf16(pa0, u.v, oc[0][dt], 0, 0, 0);
                oc[1][dt] = __builtin_amdgcn_mfma_f32_16x16x32_bf16(pa1, u.v, oc[1][dt], 0, 0, 0);
            }
            __builtin_amdgcn_s_setprio(0);
        }

        asm volatile("s_barrier" ::: "memory");     // B2: all reads of buf[p] done
        if (t + 2 < ntiles) stage(p);               // reuse buf[p] for phase t+2
        p ^= 1;
    }

    // ---- partial O store: O[q = qrow0 + mt*16 + lh*4 + r][d = dt*16 + lr] ----
    float* pb = (ks == 0) ? pp0 : (ks == 1) ? pp1 : (ks == 2) ? pp2 : pp3;
    #pragma unroll
    for (int mt = 0; mt < 2; ++mt)
        #pragma unroll
        for (int dt = 0; dt < 8; ++dt)
            #pragma unroll
            for (int r = 0; r < 4; ++r)
                pb[((size_t)b * LQ + qrow0 + mt * 16 + lh * 4 + r) * DD + dt * 16 + lr]
                    = oc[mt][dt][r];
}

// ---------------------------------------------------------------------------
// Reduce: outk = outv = sum of nsplit partials (p0/p1 alias outk/outv).
// ---------------------------------------------------------------------------
__global__ __launch_bounds__(256) void reduce_kernel(
    const float* __restrict__ p0, const float* __restrict__ p1,
    const float* __restrict__ p2, const float* __restrict__ p3,
    float* __restrict__ outk, float* __restrict__ outv, int nsplit)
{
    const int b = blockIdx.x & 7;
    const size_t j = (size_t)b * (LQ * DD) + ((size_t)(blockIdx.x >> 3) * 256 + threadIdx.x) * 4;
    f4 v = *(const f4*)&p0[j] + *(const f4*)&p1[j];
    if (nsplit == 4) v += *(const f4*)&p2[j] + *(const f4*)&p3[j];
    *(f4*)&outk[j] = v;
    *(f4*)&outv[j] = v;
}

extern "C" void kernel_launch(void* const* d_in, const int* in_sizes, int n_in,
                              void* d_out, int out_size, void* d_ws, size_t ws_size,
                              hipStream_t stream) {
    const float* x = (const float*)d_in[0];
    const float* W = (const float*)d_in[1];
    const float* bias = (const float*)d_in[2];

    float* out = (float*)d_out;
    const size_t NQ = (size_t)NB * LQ * DD;
    float* qf = out;            // output 0: q
    float* outk = out + NQ;     // output 1: k
    float* outv = out + 2 * NQ; // output 2: v

    char* ws = (char*)d_ws;
    __hip_bfloat16* proj  = (__hip_bfloat16*)ws;                          // 8 MB (swizzled, -2x)
    __hip_bfloat16* projT = (__hip_bfloat16*)(ws + 8u * 1024 * 1024);     // 8 MB (swizzled)
    __hip_bfloat16* qb    = (__hip_bfloat16*)(ws + 16u * 1024 * 1024);    // 4 MB
    float* psq            = (float*)(ws + 20u * 1024 * 1024);             // 128 KB
    float* qsq            = (float*)(ws + 20u * 1024 * 1024 + 256u * 1024); // 64 KB
    float* pw2            = (float*)(ws + 24u * 1024 * 1024);             // 8 MB partial
    float* pw3            = (float*)(ws + 32u * 1024 * 1024);             // 8 MB partial

    const int nsplit = (ws_size >= (40ull << 20)) ? 4 : 2;
    const int keys_per = LL / nsplit;

    hipLaunchKernelGGL(projA_kernel, dim3((NB * LL + NB * LQ) / 64), dim3(256), 0, stream,
                       x, W, bias, proj, projT, qb, qf, psq, qsq);
    // grid = 8 batches x 8 q-tiles x nsplit key-slices (matches kernel decode)
    hipLaunchKernelGGL(fused_kernel, dim3(64 * nsplit), dim3(512), 0, stream,
                       proj, projT, qb, psq, qsq, outk, outv, pw2, pw3, keys_per);
    hipLaunchKernelGGL(reduce_kernel, dim3(2048), dim3(256), 0, stream,
                       outk, outv, pw2, pw3, outk, outv, nsplit);
}

// Round 15
// 75.597 us; speedup vs baseline: 3.3928x; 1.0190x over previous
//
#include <hip/hip_runtime.h>
#include <hip/hip_bf16.h>
#include <stdint.h>

#define NB 8
#define LL 4096
#define LQ 2048
#define DD 128

typedef __attribute__((ext_vector_type(8))) short short8;   // bf16x8 MFMA frag
typedef __attribute__((ext_vector_type(4))) short short4v;  // bf16x4
typedef __attribute__((ext_vector_type(4))) float f4;
typedef __attribute__((ext_vector_type(2))) unsigned int u2;

typedef const __attribute__((address_space(1))) unsigned int guint_t;
typedef __attribute__((address_space(3))) unsigned int luint_t;

__device__ __forceinline__ short8 pack8(const float* v) {
    __hip_bfloat16 h[8];
    #pragma unroll
    for (int j = 0; j < 8; ++j) h[j] = __float2bfloat16(v[j]);
    return *(short8*)h;
}

// ---------------------------------------------------------------------------
// Kernel A (MFMA): proj_sw = swizzled(-2 * (x@W^T + b)), projT_sw = unscaled
//   d-major transpose (swizzled), q = avgpool2(x)@W^T + b.  (unchanged, ~8us)
// ---------------------------------------------------------------------------
__global__ __launch_bounds__(256) void projA_kernel(
    const float* __restrict__ x, const float* __restrict__ W,
    const float* __restrict__ bias,
    __hip_bfloat16* __restrict__ proj_sw, __hip_bfloat16* __restrict__ projT_sw,
    __hip_bfloat16* __restrict__ qb, float* __restrict__ qf,
    float* __restrict__ psq, float* __restrict__ qsq)
{
    __shared__ __hip_bfloat16 Wlds[128 * 128];      // 32 KB, XOR-swizzled
    __shared__ __hip_bfloat16 Tt[4][128 * 16];      // 4 KB per-wave transpose tile

    const int tid = threadIdx.x;
    const int lane = tid & 63, w = tid >> 6;
    const int lr = lane & 15, lh = lane >> 4;       // frag row / k-chunk

    #pragma unroll
    for (int k = 0; k < 16; ++k) {
        const int f = k * 1024 + tid * 4;           // flat f32 index
        const int e = f >> 7, col = f & 127;
        f4 v = *(const f4*)&W[f];
        __hip_bfloat16 h[4];
        #pragma unroll
        for (int j = 0; j < 4; ++j) h[j] = __float2bfloat16(v[j]);
        const int byte = e * 256 + (((col * 2)) ^ ((e & 7) << 4));
        *(u2*)((char*)Wlds + byte) = *(u2*)h;
    }
    float bv[8];
    #pragma unroll
    for (int nt = 0; nt < 8; ++nt) bv[nt] = bias[nt * 16 + lr];
    __syncthreads();

    const int tile = blockIdx.x;                    // 768 blocks, 1 tile each
    const int row0 = tile * 64 + w * 16;            // wave's 16 rows
    const bool qmode = tile >= (NB * LL / 64);      // >= 512

    short8 a[4];
    if (!qmode) {
        const float* src = x + (size_t)(row0 + lr) * DD;
        #pragma unroll
        for (int ks = 0; ks < 4; ++ks) {
            float t[8];
            *(f4*)&t[0] = *(const f4*)&src[ks * 32 + lh * 8];
            *(f4*)&t[4] = *(const f4*)&src[ks * 32 + lh * 8 + 4];
            a[ks] = pack8(t);
        }
    } else {
        const int gq = row0 - NB * LL + lr;         // global q row
        const int b = gq >> 11, l = gq & 2047;
        const float* s0 = x + ((size_t)b * LL + 2 * l) * DD;
        #pragma unroll
        for (int ks = 0; ks < 4; ++ks) {
            float t[8];
            f4 u0 = *(const f4*)&s0[ks * 32 + lh * 8];
            f4 u1 = *(const f4*)&s0[ks * 32 + lh * 8 + 4];
            f4 v0 = *(const f4*)&s0[DD + ks * 32 + lh * 8];
            f4 v1 = *(const f4*)&s0[DD + ks * 32 + lh * 8 + 4];
            *(f4*)&t[0] = (u0 + v0) * 0.5f;
            *(f4*)&t[4] = (u1 + v1) * 0.5f;
            a[ks] = pack8(t);
        }
    }

    f4 acc[8] = {};
    #pragma unroll
    for (int nt = 0; nt < 8; ++nt) {
        const int e = nt * 16 + lr;
        #pragma unroll
        for (int ks = 0; ks < 4; ++ks) {
            const int byte = e * 256 + ((ks * 64 + lh * 16) ^ ((lr & 7) << 4));
            short8 bk = *(const short8*)((char*)Wlds + byte);
            acc[nt] = __builtin_amdgcn_mfma_f32_16x16x32_bf16(a[ks], bk, acc[nt], 0, 0, 0);
        }
    }

    __hip_bfloat16 h[8][4];
    f4 rn = {0.f, 0.f, 0.f, 0.f};
    #pragma unroll
    for (int nt = 0; nt < 8; ++nt)
        #pragma unroll
        for (int r = 0; r < 4; ++r) {
            float v = acc[nt][r] + bv[nt];
            acc[nt][r] = v;
            h[nt][r] = __float2bfloat16(v);
            float vb = __bfloat162float(h[nt][r]);
            rn[r] += vb * vb;
        }
    #pragma unroll
    for (int m = 1; m < 16; m <<= 1) {
        #pragma unroll
        for (int r = 0; r < 4; ++r) rn[r] += __shfl_xor(rn[r], m);
    }

    if (!qmode) {
        const int gr = row0;
        // swizzled proj write, PRE-SCALED by -2 (exact): byte = (2d)^((row&7)<<4)
        #pragma unroll
        for (int nt = 0; nt < 8; ++nt)
            #pragma unroll
            for (int r = 0; r < 4; ++r) {
                const int row = gr + lh * 4 + r;
                const int byte = (nt * 32 + lr * 2) ^ (((lh * 4 + r) & 7) << 4);
                *(__hip_bfloat16*)((char*)proj_sw + (size_t)row * 256 + byte) =
                    __float2bfloat16(-2.0f * __bfloat162float(h[nt][r]));
            }
        if (lr == 0) *(f4*)&psq[gr + lh * 4] = rn;
        #pragma unroll
        for (int nt = 0; nt < 8; ++nt) {
            __hip_bfloat16 p[4] = {h[nt][0], h[nt][1], h[nt][2], h[nt][3]};
            *(u2*)((char*)&Tt[w][0] + (nt * 16 + lr) * 32 + lh * 8) = *(u2*)p;
        }
        // projT_sw: row d (8192 B), 128B tile-rows, 8B-block XOR by (d&15)<<3
        const int b = gr >> 12, l0 = gr & 4095;
        #pragma unroll
        for (int i = 0; i < 2; ++i) {
            const int e = lane + i * 64;
            const int sw = (e & 15) << 3;
            char* rowbase = (char*)projT_sw + ((size_t)(b * DD + e)) * (LL * 2)
                          + (size_t)(l0 & ~63) * 2;
            const int ob = (l0 & 63) * 2;           // 16 elems -> 4 x 8B chunks
            #pragma unroll
            for (int c = 0; c < 4; ++c) {
                u2 chunk = *(u2*)((char*)&Tt[w][e * 16] + c * 8);
                *(u2*)(rowbase + ((ob + c * 8) ^ sw)) = chunk;
            }
        }
    } else {
        const int gq = row0 - NB * LL;
        #pragma unroll
        for (int nt = 0; nt < 8; ++nt)
            #pragma unroll
            for (int r = 0; r < 4; ++r) {
                const size_t idx = (size_t)(gq + lh * 4 + r) * DD + nt * 16 + lr;
                qb[idx] = h[nt][r];
                qf[idx] = acc[nt][r];
            }
        if (lr == 0) *(f4*)&qsq[gq + lh * 4] = rn;
    }
}

// ---------------------------------------------------------------------------
// Kernel B: R13's verified 2-mtile kernel with 128-key phases (8 phases
//   instead of 16) — the decisive test of the per-phase-overhead hypothesis.
//   Per-sub math byte-identical to R13 (4 subs/phase). Stage = 8 DMA/wave,
//   counted vmcnt(8). LDS 136KB: 2x32KB pbuf + 2x32KB tbuf + 8KB psbuf.
//   tbuf rows are 256B = 2 x 128B tile-rows, XOR confined to each tile-row.
// ---------------------------------------------------------------------------
__global__ __launch_bounds__(512, 2) void fused_kernel(
    const __hip_bfloat16* __restrict__ proj_sw, const __hip_bfloat16* __restrict__ projT_sw,
    const __hip_bfloat16* __restrict__ qb, const float* __restrict__ psq,
    const float* __restrict__ qsq,
    float* __restrict__ pp0, float* __restrict__ pp1,
    float* __restrict__ pp2, float* __restrict__ pp3, int keys_per)
{
    __shared__ __hip_bfloat16 pbuf[2][16384];       // 2 x 32 KB proj tile (swizzled rows)
    __shared__ __hip_bfloat16 tbuf[2][16384];       // 2 x 32 KB projT tile (256B rows, swz)
    __shared__ __align__(16) float psbuf[2048];     // 8 KB

    const int bid = blockIdx.x;
    const int b = bid & 7;                          // XCD-pinned batch
    const int qt8 = (bid >> 3) & 7;
    const int ks = bid >> 6;                        // key slice (0..nsplit-1)
    const int tid = threadIdx.x;
    const int w = tid >> 6, lane = tid & 63;        // wave 0..7
    const int lr = lane & 15, lh = lane >> 4;

    const int qrow0 = qt8 * 256 + w * 32;           // wave's 32 q rows (2 mtiles)
    const int key0 = ks * keys_per;
    const int ntiles = keys_per / 128;              // 128-key phases

    const char* psw = (const char*)proj_sw + (size_t)b * LL * 256;
    const char* ptbsw = (const char*)projT_sw + (size_t)b * DD * LL * 2;
    const float* psb = psq + b * LL;

    // psq slice -> LDS (prologue only; NO global reg-loads inside the loop)
    for (int i = tid; i < keys_per; i += 512) psbuf[i] = psb[key0 + i];

    // q fragments (GEMM1 B-operand), 2 mtiles + norms
    short8 aq[2][4];
    const __hip_bfloat16* qbase = qb + ((size_t)b * LQ + qrow0) * DD;
    #pragma unroll
    for (int mt = 0; mt < 2; ++mt)
        #pragma unroll
        for (int kss = 0; kss < 4; ++kss)
            aq[mt][kss] = *(const short8*)&qbase[(size_t)(mt * 16 + lr) * DD + kss * 32 + lh * 8];
    const float qn0 = qsq[b * LQ + qrow0 + lr];
    const float qn1 = qsq[b * LQ + qrow0 + 16 + lr];

    __syncthreads();                                // psbuf visible; drains prologue vmem

    // staging: per phase per wave 8 DMA (4 pbuf rows-chunks + 4 tbuf row-quads)
    const char* sp = psw + (size_t)key0 * 256 + w * 4096;       // wave's 4KB pbuf chunk
    const int trow = w * 16 + (lane >> 4);                      // tbuf: 4 rows per inst
    const char* st = ptbsw + (size_t)trow * (LL * 2)
                   + (size_t)key0 * 2 + (lane & 15) * 16;
    auto stage = [&](int buf) {
        #pragma unroll
        for (int j = 0; j < 4; ++j)
            __builtin_amdgcn_global_load_lds(
                (guint_t*)(sp + j * 1024 + lane * 16),
                (luint_t*)&pbuf[buf][w * 2048 + j * 512 + lane * 8], 16, 0, 0);
        #pragma unroll
        for (int j = 0; j < 4; ++j)
            __builtin_amdgcn_global_load_lds(
                (guint_t*)(st + (size_t)j * 4 * (LL * 2)),
                (luint_t*)&tbuf[buf][(w * 16 + j * 4) * 128 + lane * 8], 16, 0, 0);
        sp += 128 * 256;                            // next 128-key phase
        st += 128 * 2;
    };

    stage(0);
    stage(1);                                       // depth-1 prefetch: 16 outstanding

    f4 oc[2][8] = {};                               // [mt][dt]
    int p = 0;

    for (int t = 0; t < ntiles; ++t) {
        // counted wait: phase t's 8 DMAs done; phase t+1's 8 stay in flight
        if (t + 1 < ntiles) asm volatile("s_waitcnt vmcnt(8)" ::: "memory");
        else                asm volatile("s_waitcnt vmcnt(0)" ::: "memory");
        asm volatile("s_barrier" ::: "memory");     // B1: all waves' t-data visible

        #pragma unroll
        for (int sub = 0; sub < 4; ++sub) {
            // ---- GEMM1 (swapped, -2-prescaled K, C-init = qn+pn -> power) ----
            f4 pn0 = *(const f4*)&psbuf[t * 128 + sub * 32 + lh * 4];
            f4 pn1 = *(const f4*)&psbuf[t * 128 + sub * 32 + 16 + lh * 4];
            f4 s00, s01, s10, s11;                  // s[kt][mt]
            #pragma unroll
            for (int r = 0; r < 4; ++r) {
                s00[r] = qn0 + pn0[r];  s01[r] = qn1 + pn0[r];
                s10[r] = qn0 + pn1[r];  s11[r] = qn1 + pn1[r];
            }
            __builtin_amdgcn_s_setprio(1);
            #pragma unroll
            for (int kss = 0; kss < 4; ++kss) {
                const int off = (kss * 64 + lh * 16) ^ ((lr & 7) << 4);
                short8 ak0 = *(const short8*)((const char*)pbuf[p] + (sub * 32 + lr) * 256 + off);
                short8 ak1 = *(const short8*)((const char*)pbuf[p] + (sub * 32 + 16 + lr) * 256 + off);
                s00 = __builtin_amdgcn_mfma_f32_16x16x32_bf16(ak0, aq[0][kss], s00, 0, 0, 0);
                s01 = __builtin_amdgcn_mfma_f32_16x16x32_bf16(ak0, aq[1][kss], s01, 0, 0, 0);
                s10 = __builtin_amdgcn_mfma_f32_16x16x32_bf16(ak1, aq[0][kss], s10, 0, 0, 0);
                s11 = __builtin_amdgcn_mfma_f32_16x16x32_bf16(ak1, aq[1][kss], s11, 0, 0, 0);
            }
            __builtin_amdgcn_s_setprio(0);

            // ---- transform: power -> exp(-sqrt(max(power,0))), in (0,1] ----
            short8 pa0, pa1;
            {
                alignas(16) __hip_bfloat16 hh[8];
                #pragma unroll
                for (int r = 0; r < 4; ++r) {
                    hh[r]     = __float2bfloat16(__expf(-__builtin_amdgcn_sqrtf(fmaxf(s00[r], 0.0f))));
                    hh[4 + r] = __float2bfloat16(__expf(-__builtin_amdgcn_sqrtf(fmaxf(s10[r], 0.0f))));
                }
                pa0 = *(short8*)hh;
                #pragma unroll
                for (int r = 0; r < 4; ++r) {
                    hh[r]     = __float2bfloat16(__expf(-__builtin_amdgcn_sqrtf(fmaxf(s01[r], 0.0f))));
                    hh[4 + r] = __float2bfloat16(__expf(-__builtin_amdgcn_sqrtf(fmaxf(s11[r], 0.0f))));
                }
                pa1 = *(short8*)hh;
            }

            // ---- GEMM2: O += sim @ proj; B-frag shared across both mtiles ----
            // tbuf row = 256B (2 x 128B tile-rows); XOR within each tile-row.
            __builtin_amdgcn_s_setprio(1);
            #pragma unroll
            for (int dt = 0; dt < 8; ++dt) {
                const char* rowp = (const char*)tbuf[p] + (dt * 16 + lr) * 256;
                const int sw = lr << 3;
                const int hi = (sub >> 1) * 128;
                union { short8 v; short4v h[2]; } u;
                u.h[0] = *(const short4v*)(rowp + hi + ((lh * 8 + (sub & 1) * 64) ^ sw));
                u.h[1] = *(const short4v*)(rowp + hi + ((lh * 8 + 32 + (sub & 1) * 64) ^ sw));
                oc[0][dt] = __builtin_amdgcn_mfma_f32_16x16x32_bf16(pa0, u.v, oc[0][dt], 0, 0, 0);
                oc[1][dt] = __builtin_amdgcn_mfma_f32_16x16x32_bf16(pa1, u.v, oc[1][dt], 0, 0, 0);
            }
            __builtin_amdgcn_s_setprio(0);
        }

        asm volatile("s_barrier" ::: "memory");     // B2: all reads of buf[p] done
        if (t + 2 < ntiles) stage(p);               // reuse buf[p] for phase t+2
        p ^= 1;
    }

    // ---- partial O store: O[q = qrow0 + mt*16 + lh*4 + r][d = dt*16 + lr] ----
    float* pb = (ks == 0) ? pp0 : (ks == 1) ? pp1 : (ks == 2) ? pp2 : pp3;
    #pragma unroll
    for (int mt = 0; mt < 2; ++mt)
        #pragma unroll
        for (int dt = 0; dt < 8; ++dt)
            #pragma unroll
            for (int r = 0; r < 4; ++r)
                pb[((size_t)b * LQ + qrow0 + mt * 16 + lh * 4 + r) * DD + dt * 16 + lr]
                    = oc[mt][dt][r];
}

// ---------------------------------------------------------------------------
// Reduce: outk = outv = sum of nsplit partials (p0/p1 alias outk/outv).
// ---------------------------------------------------------------------------
__global__ __launch_bounds__(256) void reduce_kernel(
    const float* __restrict__ p0, const float* __restrict__ p1,
    const float* __restrict__ p2, const float* __restrict__ p3,
    float* __restrict__ outk, float* __restrict__ outv, int nsplit)
{
    const int b = blockIdx.x & 7;
    const size_t j = (size_t)b * (LQ * DD) + ((size_t)(blockIdx.x >> 3) * 256 + threadIdx.x) * 4;
    f4 v = *(const f4*)&p0[j] + *(const f4*)&p1[j];
    if (nsplit == 4) v += *(const f4*)&p2[j] + *(const f4*)&p3[j];
    *(f4*)&outk[j] = v;
    *(f4*)&outv[j] = v;
}

extern "C" void kernel_launch(void* const* d_in, const int* in_sizes, int n_in,
                              void* d_out, int out_size, void* d_ws, size_t ws_size,
                              hipStream_t stream) {
    const float* x = (const float*)d_in[0];
    const float* W = (const float*)d_in[1];
    const float* bias = (const float*)d_in[2];

    float* out = (float*)d_out;
    const size_t NQ = (size_t)NB * LQ * DD;
    float* qf = out;            // output 0: q
    float* outk = out + NQ;     // output 1: k
    float* outv = out + 2 * NQ; // output 2: v

    char* ws = (char*)d_ws;
    __hip_bfloat16* proj  = (__hip_bfloat16*)ws;                          // 8 MB (swizzled, -2x)
    __hip_bfloat16* projT = (__hip_bfloat16*)(ws + 8u * 1024 * 1024);     // 8 MB (swizzled)
    __hip_bfloat16* qb    = (__hip_bfloat16*)(ws + 16u * 1024 * 1024);    // 4 MB
    float* psq            = (float*)(ws + 20u * 1024 * 1024);             // 128 KB
    float* qsq            = (float*)(ws + 20u * 1024 * 1024 + 256u * 1024); // 64 KB
    float* pw2            = (float*)(ws + 24u * 1024 * 1024);             // 8 MB partial
    float* pw3            = (float*)(ws + 32u * 1024 * 1024);             // 8 MB partial

    const int nsplit = (ws_size >= (40ull << 20)) ? 4 : 2;
    const int keys_per = LL / nsplit;

    hipLaunchKernelGGL(projA_kernel, dim3((NB * LL + NB * LQ) / 64), dim3(256), 0, stream,
                       x, W, bias, proj, projT, qb, qf, psq, qsq);
    // grid = 8 batches x 8 q-tiles x nsplit key-slices (matches kernel decode)
    hipLaunchKernelGGL(fused_kernel, dim3(64 * nsplit), dim3(512), 0, stream,
                       proj, projT, qb, psq, qsq, outk, outv, pw2, pw3, keys_per);
    hipLaunchKernelGGL(reduce_kernel, dim3(2048), dim3(256), 0, stream,
                       outk, outv, pw2, pw3, outk, outv, nsplit);
}